// Round 5
// baseline (656.292 us; speedup 1.0000x reference)
//
#include <hip/hip_runtime.h>

#define BB  256
#define TT  500
#define ENC 700
#define ENC_PAD 704   // rows 700..703 of w1t are zeros (gather padding target)
#define HID 128
#define LMAX 80       // per-row index-list capacity; mean n=35, sd 4.1 -> 11 sigma

// ---------------------------------------------------------------------------
// Kernel 1: transpose w1 (HID, ENC) -> w1t (ENC_PAD, HID); pad rows = 0
// ---------------------------------------------------------------------------
__global__ __launch_bounds__(128) void transpose_w1_kernel(const float* __restrict__ w1,
                                                           float* __restrict__ w1t) {
    int c = blockIdx.x;      // 0..ENC_PAD-1
    int h = threadIdx.x;     // 0..HID-1
    w1t[c * HID + h] = (c < ENC) ? w1[h * ENC + c] : 0.0f;
}

// ---------------------------------------------------------------------------
// Kernel 2a: compress x rows into ascending column-index lists (ushort),
// padded to LMAX with the zero column (ENC). One wave per row. (Unchanged
// from round 4 — proven exact.)
// ---------------------------------------------------------------------------
__global__ __launch_bounds__(256) void compress_kernel(const float* __restrict__ x,
                                                       ushort* __restrict__ lists,
                                                       int* __restrict__ ncnt) {
    __shared__ ushort lds[4][LMAX];
    const int lane = threadIdx.x & 63;
    const int w = threadIdx.x >> 6;
    const int r = blockIdx.x * 4 + w;                 // row = b*TT + t
    const float* xrow = x + (size_t)r * ENC;
    const unsigned long long lt = (1ull << lane) - 1ull;

    float xv[11];
    #pragma unroll
    for (int k = 0; k < 11; ++k) {
        int c = k * 64 + lane;
        xv[k] = (c < ENC) ? xrow[c] : 0.0f;
    }
    int base = 0;
    #pragma unroll
    for (int k = 0; k < 11; ++k) {
        bool act = (xv[k] != 0.0f);
        unsigned long long m = __ballot(act);
        if (act) {
            int pos = base + (int)__popcll(m & lt);
            if (pos < LMAX) lds[w][pos] = (ushort)(k * 64 + lane);
        }
        base += (int)__popcll(m);
    }
    int n = (base < LMAX) ? base : LMAX;
    for (int p = n + lane; p < LMAX; p += 64) lds[w][p] = (ushort)ENC;  // zero-col pad
    if (lane == 0) ncnt[r] = n;
    if (lane < LMAX / 2)
        ((uint*)lists)[(size_t)r * (LMAX / 2) + lane] =
            ((const uint*)lds)[w * (LMAX / 2) + lane];
}

// ---------------------------------------------------------------------------
// Kernel 2b: gather v2 — XOR-swizzled LDS weight slices (conflict-free).
// Block owns a 16-channel slice of w1t in LDS (stride 18 dwords) and 512
// rows. Physical float2-slot for (c, k) is k ^ ((c>>4)&7): two columns
// collide on a bank only if c = c' (mod 128) -> conflicts ~eliminated.
// Ordered ascending adds per channel (bit-exact). LDS 61.2 KB -> 2 blocks/CU.
// ---------------------------------------------------------------------------
#define GROWS 512
#define GRP   64
#define QCH   16
#define WST   18

__device__ __forceinline__ int swadr(int c, int k) {
    // dword address of channels {2k,2k+1} of column c in w1q
    return c * WST + 2 * (k ^ ((c >> 4) & 7));
}

__global__ __launch_bounds__(256) void gather2_kernel(const ushort* __restrict__ lists,
                                                      const int* __restrict__ ncnt,
                                                      const float* __restrict__ w1t,
                                                      float* __restrict__ h) {
    __shared__ float  w1q[ENC_PAD * WST];   // 50688 B
    __shared__ ushort ll[GRP * LMAX];       // 10240 B
    __shared__ int    nb[GRP];

    const int tid = threadIdx.x;
    const int lane = tid & 63;
    const int w = tid >> 6;
    const int q = blockIdx.y;               // channel-eighth 0..7
    const int r0b = blockIdx.x * GROWS;

    // stage the 16-channel slice, swizzled
    for (int i = tid; i < ENC_PAD * 8; i += 256) {
        int c = i >> 3, k = i & 7;
        float2 v = *(const float2*)&w1t[c * HID + q * QCH + 2 * k];
        *(float2*)&w1q[swadr(c, k)] = v;
    }

    const int k  = lane & 7;                // float2 slot -> channels 2k,2k+1
    const int rw = lane >> 3;               // row-in-wave 0..7

    for (int g = 0; g < GROWS / GRP; ++g) {
        const int r0 = r0b + g * GRP;
        __syncthreads();                    // prev group's reads done
        {
            const uint* src = (const uint*)lists + (size_t)r0 * (LMAX / 2);
            uint* dst = (uint*)ll;
            #pragma unroll
            for (int kk = 0; kk < 10; ++kk) dst[tid + kk * 256] = src[tid + kk * 256];
        }
        if (tid < GRP) nb[tid] = ncnt[r0 + tid];
        __syncthreads();

        #pragma unroll
        for (int p = 0; p < 2; ++p) {
            const int rl = p * 32 + w * 8 + rw;
            int n = nb[rl];
            n = max(n, __shfl_xor(n, 8));
            n = max(n, __shfl_xor(n, 16));
            n = max(n, __shfl_xor(n, 32));
            const int jmax = (n + 7) & ~7;

            float a0 = 0.f, a1 = 0.f;
            for (int j = 0; j < jmax; j += 8) {
                uint4 iv = *(const uint4*)&ll[rl * LMAX + j];   // 8 idx, broadcast
                int c0 = (int)(iv.x & 0xffff), c1 = (int)(iv.x >> 16);
                int c2 = (int)(iv.y & 0xffff), c3 = (int)(iv.y >> 16);
                int c4 = (int)(iv.z & 0xffff), c5 = (int)(iv.z >> 16);
                int c6 = (int)(iv.w & 0xffff), c7 = (int)(iv.w >> 16);
                float2 v0 = *(const float2*)&w1q[swadr(c0, k)];
                float2 v1 = *(const float2*)&w1q[swadr(c1, k)];
                float2 v2 = *(const float2*)&w1q[swadr(c2, k)];
                float2 v3 = *(const float2*)&w1q[swadr(c3, k)];
                float2 v4 = *(const float2*)&w1q[swadr(c4, k)];
                float2 v5 = *(const float2*)&w1q[swadr(c5, k)];
                float2 v6 = *(const float2*)&w1q[swadr(c6, k)];
                float2 v7 = *(const float2*)&w1q[swadr(c7, k)];
                // ordered ascending adds — do not reassociate (bit-exactness)
                a0 += v0.x; a1 += v0.y;
                a0 += v1.x; a1 += v1.y;
                a0 += v2.x; a1 += v2.y;
                a0 += v3.x; a1 += v3.y;
                a0 += v4.x; a1 += v4.y;
                a0 += v5.x; a1 += v5.y;
                a0 += v6.x; a1 += v6.y;
                a0 += v7.x; a1 += v7.y;
            }
            const int r = r0 + rl;
            const int b = r / TT;
            const int t = r - b * TT;
            // h layout: [b][t][ch] (batch-major for recur3's direct global reads)
            *(float2*)&h[(size_t)b * (TT * HID) + (size_t)t * HID + q * QCH + 2 * k] =
                make_float2(a0, a1);
        }
    }
}

// ---------------------------------------------------------------------------
// Kernel 3: recur v3 — no LDS on either serial chain.
// Thread tid = channel. Scan reads h[b][t][tid] straight from global into a
// 50-register prefetch array (independent coalesced loads); layer-2 pulls all
// 50 o_t values into registers before its serial chain. LDS only for the
// off-chain o_t partial reduction. Formulas verbatim from validated R3/R4.
// ---------------------------------------------------------------------------
__global__ __launch_bounds__(128) void recur3_kernel(const float* __restrict__ hgl,
                                                     const float* __restrict__ w2,
                                                     float* __restrict__ out) {
    __shared__ float vbuf[50 * 129];      // 25.8 KB, stride 129 -> conflict-free rows
    __shared__ float pbuf[2][50];

    const int b = blockIdx.x;
    const int tid = threadIdx.x;          // 0..127 = channel

    const float D   = 0.95122942450071400910f;                                 // exp(-1/20)
    const float CD  = (float)(0.13591409142295226 * 0.95122942450071400910);   // (e/20)*d
    const float CRD = (float)(-0.27182818284590452 * 0.95122942450071400910);  // (-2e/20)*d

    float ap = 0.f, aq = 0.f, rp = 0.f, rq = 0.f;   // layer-1 state (ch = tid)
    float Ap = 0.f, Aq = 0.f, Rp = 0.f, Rq = 0.f;   // layer-2 state (redundant)
    const float w2v = w2[tid];
    const float* hb = hgl + (size_t)b * (TT * HID) + tid;

    for (int chunk = 0; chunk < 10; ++chunk) {
        // prefetch the chunk's 50 h values into registers (independent loads)
        float hv[50];
        #pragma unroll
        for (int tl = 0; tl < 50; ++tl)
            hv[tl] = hb[(size_t)(chunk * 50 + tl) * HID];

        // layer-1 scan, 50 steps — pure-VALU critical path
        #pragma unroll
        for (int tl = 0; tl < 50; ++tl) {
            float y = fmaf(D, aq, CD * ap);
            aq = y;
            ap = fmaf(D, ap, hv[tl]);
            float qq = fmaf(D, rq, CRD * rp);
            float u = y + qq;
            float s = (u >= 1.0f) ? 1.0f : 0.0f;
            rq = qq;
            rp = fmaf(D, rp, s);
            vbuf[tl * 129 + tid] = s * w2v;
        }
        __syncthreads();

        // reduce o_t partials (off-chain, independent LDS reads)
        if (tid < 50) {
            const float* row = &vbuf[tid * 129];
            float a0 = 0.f, a1 = 0.f, a2 = 0.f, a3 = 0.f;
            #pragma unroll
            for (int kk = 0; kk < 64; kk += 4) {
                a0 += row[kk]; a1 += row[kk + 1]; a2 += row[kk + 2]; a3 += row[kk + 3];
            }
            pbuf[0][tid] = (a0 + a1) + (a2 + a3);
        } else if (tid >= 64 && tid < 114) {
            const float* row = &vbuf[(tid - 64) * 129 + 64];
            float a0 = 0.f, a1 = 0.f, a2 = 0.f, a3 = 0.f;
            #pragma unroll
            for (int kk = 0; kk < 64; kk += 4) {
                a0 += row[kk]; a1 += row[kk + 1]; a2 += row[kk + 2]; a3 += row[kk + 3];
            }
            pbuf[1][tid - 64] = (a0 + a1) + (a2 + a3);
        }
        __syncthreads();

        // pull all 50 o_t into registers, then run the serial chain on VALU only
        float otv[50];
        #pragma unroll
        for (int tl = 0; tl < 50; ++tl)
            otv[tl] = pbuf[0][tl] + pbuf[1][tl];

        float my_s2 = 0.f;
        #pragma unroll
        for (int tl = 0; tl < 50; ++tl) {
            float ot = otv[tl];
            float y2 = fmaf(D, Aq, CD * Ap);
            Aq = y2;
            Ap = fmaf(D, Ap, ot);
            float q2 = fmaf(D, Rq, CRD * Rp);
            float u2 = y2 + q2;
            float s2 = (u2 >= 1.0f) ? 1.0f : 0.0f;
            Rq = q2;
            Rp = fmaf(D, Rp, s2);
            if (tl == tid) my_s2 = s2;
        }
        if (tid < 50) out[(size_t)b * TT + chunk * 50 + tid] = my_s2;
        // next chunk's vbuf writes are ordered by its pre-reduce barrier;
        // pbuf is rewritten only after all threads pass that barrier.
    }
}

// ---------------------------------------------------------------------------
// Fallback spmm (ws too small): round-3 kernel, h layout updated to [b][t][ch]
// ---------------------------------------------------------------------------
__global__ __launch_bounds__(256) void spmm3_kernel(const float* __restrict__ x,
                                                    const float* __restrict__ w1t,
                                                    float* __restrict__ h) {
    __shared__ ushort lists[4][144];
    const int lane = threadIdx.x & 63;
    const int w = threadIdx.x >> 6;
    const int r = blockIdx.x * 4 + w;
    const float* xrow = x + (size_t)r * ENC;
    const unsigned long long lt = (1ull << lane) - 1ull;

    float xv[11];
    #pragma unroll
    for (int kk = 0; kk < 11; ++kk) {
        int c = kk * 64 + lane;
        xv[kk] = (c < ENC) ? xrow[c] : 0.0f;
    }
    int base = 0;
    #pragma unroll
    for (int kk = 0; kk < 11; ++kk) {
        bool act = (xv[kk] != 0.0f);
        unsigned long long m = __ballot(act);
        if (act) {
            int pos = base + (int)__popcll(m & lt);
            if (pos < 128) lists[w][pos] = (ushort)(kk * 64 + lane);
        }
        base += (int)__popcll(m);
    }
    int n = (base < 128) ? base : 128;
    int npad = (n + 15) & ~15;
    if (lane < npad - n) lists[w][n + lane] = (ushort)ENC;
    __syncthreads();

    float accx = 0.f, accy = 0.f;
    for (int j = 0; j < npad; j += 16) {
        int c0  = lists[w][j + 0],  c1  = lists[w][j + 1];
        int c2  = lists[w][j + 2],  c3  = lists[w][j + 3];
        int c4  = lists[w][j + 4],  c5  = lists[w][j + 5];
        int c6  = lists[w][j + 6],  c7  = lists[w][j + 7];
        int c8  = lists[w][j + 8],  c9  = lists[w][j + 9];
        int c10 = lists[w][j + 10], c11 = lists[w][j + 11];
        int c12 = lists[w][j + 12], c13 = lists[w][j + 13];
        int c14 = lists[w][j + 14], c15 = lists[w][j + 15];
        float2 t0  = ((const float2*)(w1t + (size_t)c0  * HID))[lane];
        float2 t1  = ((const float2*)(w1t + (size_t)c1  * HID))[lane];
        float2 t2  = ((const float2*)(w1t + (size_t)c2  * HID))[lane];
        float2 t3  = ((const float2*)(w1t + (size_t)c3  * HID))[lane];
        float2 t4  = ((const float2*)(w1t + (size_t)c4  * HID))[lane];
        float2 t5  = ((const float2*)(w1t + (size_t)c5  * HID))[lane];
        float2 t6  = ((const float2*)(w1t + (size_t)c6  * HID))[lane];
        float2 t7  = ((const float2*)(w1t + (size_t)c7  * HID))[lane];
        float2 t8  = ((const float2*)(w1t + (size_t)c8  * HID))[lane];
        float2 t9  = ((const float2*)(w1t + (size_t)c9  * HID))[lane];
        float2 t10 = ((const float2*)(w1t + (size_t)c10 * HID))[lane];
        float2 t11 = ((const float2*)(w1t + (size_t)c11 * HID))[lane];
        float2 t12 = ((const float2*)(w1t + (size_t)c12 * HID))[lane];
        float2 t13 = ((const float2*)(w1t + (size_t)c13 * HID))[lane];
        float2 t14 = ((const float2*)(w1t + (size_t)c14 * HID))[lane];
        float2 t15 = ((const float2*)(w1t + (size_t)c15 * HID))[lane];
        accx += t0.x;  accy += t0.y;  accx += t1.x;  accy += t1.y;
        accx += t2.x;  accy += t2.y;  accx += t3.x;  accy += t3.y;
        accx += t4.x;  accy += t4.y;  accx += t5.x;  accy += t5.y;
        accx += t6.x;  accy += t6.y;  accx += t7.x;  accy += t7.y;
        accx += t8.x;  accy += t8.y;  accx += t9.x;  accy += t9.y;
        accx += t10.x; accy += t10.y; accx += t11.x; accy += t11.y;
        accx += t12.x; accy += t12.y; accx += t13.x; accy += t13.y;
        accx += t14.x; accy += t14.y; accx += t15.x; accy += t15.y;
    }
    int b = r / TT;
    int t = r - b * TT;
    float2* dst = (float2*)(h + (size_t)b * (TT * HID) + (size_t)t * HID);
    dst[lane] = make_float2(accx, accy);
}

// ---------------------------------------------------------------------------
extern "C" void kernel_launch(void* const* d_in, const int* in_sizes, int n_in,
                              void* d_out, int out_size, void* d_ws, size_t ws_size,
                              hipStream_t stream) {
    const float* x  = (const float*)d_in[0];   // (B, T, ENC) binary fp32
    const float* w1 = (const float*)d_in[1];   // (HID, ENC)
    const float* w2 = (const float*)d_in[2];   // (1, HID)
    float* out = (float*)d_out;                // (B, T, 1)

    const size_t H_ELEMS   = (size_t)TT * BB * HID;
    const size_t W1T_ELEMS = (size_t)ENC_PAD * HID;
    float* h   = (float*)d_ws;
    float* w1t = h + H_ELEMS;
    char* base2 = (char*)(w1t + W1T_ELEMS);
    ushort* lists = (ushort*)base2;                           // 20.48 MB
    int* ncnt = (int*)(base2 + (size_t)BB * TT * LMAX * 2);   // 0.51 MB
    const size_t NEED = (size_t)(base2 - (char*)d_ws) +
                        (size_t)BB * TT * LMAX * 2 + (size_t)BB * TT * 4;

    hipLaunchKernelGGL(transpose_w1_kernel, dim3(ENC_PAD), dim3(HID), 0, stream, w1, w1t);
    if (ws_size >= NEED) {
        hipLaunchKernelGGL(compress_kernel, dim3((BB * TT) / 4), dim3(256), 0, stream,
                           x, lists, ncnt);
        hipLaunchKernelGGL(gather2_kernel, dim3(BB * TT / GROWS, HID / QCH), dim3(256),
                           0, stream, lists, ncnt, w1t, h);
    } else {
        hipLaunchKernelGGL(spmm3_kernel, dim3((BB * TT) / 4), dim3(256), 0, stream,
                           x, w1t, h);
    }
    hipLaunchKernelGGL(recur3_kernel, dim3(BB), dim3(128), 0, stream, h, w2, out);
}

// Round 6
// 650.341 us; speedup vs baseline: 1.0091x; 1.0091x over previous
//
#include <hip/hip_runtime.h>

#define BB  256
#define TT  500
#define ENC 700
#define ENC_PAD 704   // rows 700..703 of w1t are zeros (gather padding target)
#define HID 128
#define LMAX 80       // per-row index-list capacity; mean n=35, sd 4.1 -> 11 sigma

#define GROWS 512
#define GRP   64
#define QCH   16
#define WST   18      // dwords per 16-ch column slice (16 + 2 pad)
#define CBYTES (WST * 4)   // 72 bytes per column slice
#define LSTRIDE 84    // uints per row in ll (84*4 B: rows land on distinct banks)

// ---------------------------------------------------------------------------
// Kernel 1: transpose w1 (HID, ENC) -> w1t (ENC_PAD, HID); pad rows = 0
// ---------------------------------------------------------------------------
__global__ __launch_bounds__(128) void transpose_w1_kernel(const float* __restrict__ w1,
                                                           float* __restrict__ w1t) {
    int c = blockIdx.x;      // 0..ENC_PAD-1
    int h = threadIdx.x;     // 0..HID-1
    w1t[c * HID + h] = (c < ENC) ? w1[h * ENC + c] : 0.0f;
}

// ---------------------------------------------------------------------------
// Kernel 2a: compress x rows into ascending-order lists of PRE-SCALED BYTE
// OFFSETS (c * 72) padded to LMAX with the zero column (700*72). One wave
// per row; same proven-exact ballot compaction, uint payload.
// ---------------------------------------------------------------------------
__global__ __launch_bounds__(256) void compress2_kernel(const float* __restrict__ x,
                                                        uint* __restrict__ lists,
                                                        int* __restrict__ ncnt) {
    __shared__ __align__(16) uint lds[4][LMAX];
    const int lane = threadIdx.x & 63;
    const int w = threadIdx.x >> 6;
    const int r = blockIdx.x * 4 + w;                 // row = b*TT + t
    const float* xrow = x + (size_t)r * ENC;
    const unsigned long long lt = (1ull << lane) - 1ull;

    float xv[11];
    #pragma unroll
    for (int k = 0; k < 11; ++k) {
        int c = k * 64 + lane;
        xv[k] = (c < ENC) ? xrow[c] : 0.0f;
    }
    int base = 0;
    #pragma unroll
    for (int k = 0; k < 11; ++k) {
        bool act = (xv[k] != 0.0f);
        unsigned long long m = __ballot(act);
        if (act) {
            int pos = base + (int)__popcll(m & lt);
            if (pos < LMAX) lds[w][pos] = (uint)((k * 64 + lane) * CBYTES);
        }
        base += (int)__popcll(m);
    }
    int n = (base < LMAX) ? base : LMAX;
    for (int p = n + lane; p < LMAX; p += 64) lds[w][p] = (uint)(ENC * CBYTES);
    if (lane == 0) ncnt[r] = n;
    if (lane < LMAX / 4)   // 20 uint4 per row, coalesced
        ((uint4*)lists)[(size_t)r * (LMAX / 4) + lane] = ((const uint4*)lds[w])[lane];
}

// ---------------------------------------------------------------------------
// Kernel 2b: gather v3 — minimal VALU per LDS read.
// Block owns a 16-channel slice of w1t in LDS (stride 18 dwords) + 512 rows.
// Lists hold pre-scaled byte offsets: per column = 1 v_add + 1 ds_read_b64 +
// 2 ordered adds. Index loads are uint4 ds_read_b128 from stride-84 rows
// (distinct banks per row-group). Ordered ascending adds per channel
// (bit-exact). LDS 72.2 KB -> 2 blocks/CU (8 waves).
// ---------------------------------------------------------------------------
__global__ __launch_bounds__(256, 2) void gather3_kernel(const uint* __restrict__ lists,
                                                         const int* __restrict__ ncnt,
                                                         const float* __restrict__ w1t,
                                                         float* __restrict__ h) {
    __shared__ __align__(16) float w1q[ENC_PAD * WST];   // 50688 B
    __shared__ __align__(16) uint  ll[GRP * LSTRIDE];    // 21504 B
    __shared__ int nb[GRP];

    const int tid = threadIdx.x;
    const int lane = tid & 63;
    const int w = tid >> 6;
    const int q = blockIdx.y;               // channel-eighth 0..7
    const int r0b = blockIdx.x * GROWS;

    // stage the 16-channel slice (incl. zero rows 700..703)
    for (int i = tid; i < ENC_PAD * 8; i += 256) {
        int c = i >> 3, k = i & 7;
        *(float2*)&w1q[c * WST + 2 * k] = *(const float2*)&w1t[c * HID + q * QCH + 2 * k];
    }

    const int k  = lane & 7;                // channel pair 2k,2k+1
    const int rw = lane >> 3;               // row-in-wave 0..7
    const int ko = 8 * k;                   // byte offset within a column slice
    const char* w1qb = (const char*)w1q;

    for (int g = 0; g < GROWS / GRP; ++g) {
        const int r0 = r0b + g * GRP;
        __syncthreads();                    // prev group's reads done
        {   // stage 64 rows' offset lists: 1280 uint4, coalesced
            const uint4* src = (const uint4*)(lists + (size_t)r0 * LMAX);
            #pragma unroll
            for (int kk = 0; kk < 5; ++kk) {
                int idx = tid + kk * 256;          // 0..1279
                int row = idx / 20, col = idx - row * 20;
                *(uint4*)&ll[row * LSTRIDE + col * 4] = src[idx];
            }
        }
        if (tid < GRP) nb[tid] = ncnt[r0 + tid];
        __syncthreads();

        #pragma unroll
        for (int p = 0; p < 2; ++p) {       // 2 passes x (4 waves x 8 rows)
            const int rl = p * 32 + w * 8 + rw;
            int n = nb[rl];
            n = max(n, __shfl_xor(n, 8));
            n = max(n, __shfl_xor(n, 16));
            n = max(n, __shfl_xor(n, 32));
            const int jmax = (n + 7) & ~7;  // wave-uniform; pad reads are exact +0
            const uint* lrow = &ll[rl * LSTRIDE];

            float a0 = 0.f, a1 = 0.f;
            for (int j = 0; j < jmax; j += 8) {
                uint4 o0 = *(const uint4*)&lrow[j];       // 8 byte-offsets,
                uint4 o1 = *(const uint4*)&lrow[j + 4];   // broadcast per row-group
                float2 v0 = *(const float2*)(w1qb + (o0.x + ko));
                float2 v1 = *(const float2*)(w1qb + (o0.y + ko));
                float2 v2 = *(const float2*)(w1qb + (o0.z + ko));
                float2 v3 = *(const float2*)(w1qb + (o0.w + ko));
                float2 v4 = *(const float2*)(w1qb + (o1.x + ko));
                float2 v5 = *(const float2*)(w1qb + (o1.y + ko));
                float2 v6 = *(const float2*)(w1qb + (o1.z + ko));
                float2 v7 = *(const float2*)(w1qb + (o1.w + ko));
                // ordered ascending adds — do not reassociate (bit-exactness);
                // the two channels are independent chains (packable).
                a0 += v0.x; a1 += v0.y;
                a0 += v1.x; a1 += v1.y;
                a0 += v2.x; a1 += v2.y;
                a0 += v3.x; a1 += v3.y;
                a0 += v4.x; a1 += v4.y;
                a0 += v5.x; a1 += v5.y;
                a0 += v6.x; a1 += v6.y;
                a0 += v7.x; a1 += v7.y;
            }
            const int r = r0 + rl;
            const int b = r / TT;
            const int t = r - b * TT;
            // h layout: [t][b][ch]
            *(float2*)&h[(size_t)t * (BB * HID) + (size_t)b * HID + q * QCH + 2 * k] =
                make_float2(a0, a1);
        }
    }
}

// ---------------------------------------------------------------------------
// Kernel 3: recur v2' (validated in R4). 128 threads (2 waves), 1 ch/lane.
// h chunk (50 t) prefetched into REGISTERS (13 float4/thread) during the
// previous chunk's scan, then ds_written to a single LDS buffer.
// launch_bounds(128,1) relaxes the VGPR cap -> no scratch spill.
// ---------------------------------------------------------------------------
__global__ __launch_bounds__(128, 1) void recur2_kernel(const float* __restrict__ hgl,
                                                        const float* __restrict__ w2,
                                                        float* __restrict__ out) {
    __shared__ float hbuf[52 * 132];      // 27.5 KB
    __shared__ float vbuf[50 * 129];      // 25.8 KB
    __shared__ float pbuf[2][50];

    const int b = blockIdx.x;
    const int tid = threadIdx.x;          // 0..127 = channel

    const float D   = 0.95122942450071400910f;                                 // exp(-1/20)
    const float CD  = (float)(0.13591409142295226 * 0.95122942450071400910);   // (e/20)*d
    const float CRD = (float)(-0.27182818284590452 * 0.95122942450071400910);  // (-2e/20)*d

    float ap = 0.f, aq = 0.f, rp = 0.f, rq = 0.f;   // layer-1 state (ch = tid)
    float Ap = 0.f, Aq = 0.f, Rp = 0.f, Rq = 0.f;   // layer-2 state (redundant)
    const float w2v = w2[tid];

    const int tl0 = tid >> 5;             // 0..3: t-row within a load sweep
    const int ch0 = (tid & 31) * 4;       // float4 channel offset
    const float* hb = hgl + (size_t)b * HID + ch0;

    float4 pf[13];
    #pragma unroll
    for (int i = 0; i < 13; ++i) {        // prefetch chunk 0 (t = 0..51)
        int t = i * 4 + tl0;
        pf[i] = *(const float4*)(hb + (size_t)t * (BB * HID));
    }

    for (int chunk = 0; chunk < 10; ++chunk) {
        // 1. spill prefetched chunk to LDS
        #pragma unroll
        for (int i = 0; i < 13; ++i)
            *(float4*)&hbuf[(i * 4 + tl0) * 132 + ch0] = pf[i];
        __syncthreads();

        // 2. issue next chunk's loads (registers; consumed next iteration)
        {
            const int tb = (chunk + 1) * 50;
            #pragma unroll
            for (int i = 0; i < 13; ++i) {
                int t = tb + i * 4 + tl0;
                t = (t < TT) ? t : (TT - 1);          // clamp: harmless re-read
                pf[i] = *(const float4*)(hb + (size_t)t * (BB * HID));
            }
        }

        // 3. layer-1 scan, 50 steps
        #pragma unroll
        for (int tl = 0; tl < 50; ++tl) {
            float hv = hbuf[tl * 132 + tid];
            float y = fmaf(D, aq, CD * ap);
            aq = y;
            ap = fmaf(D, ap, hv);
            float q = fmaf(D, rq, CRD * rp);
            float u = y + q;
            float s = (u >= 1.0f) ? 1.0f : 0.0f;
            rq = q;
            rp = fmaf(D, rp, s);
            vbuf[tl * 129 + tid] = s * w2v;
        }
        __syncthreads();

        // 4. reduce o_t partials
        if (tid < 50) {
            const float* row = &vbuf[tid * 129];
            float a0 = 0.f, a1 = 0.f, a2 = 0.f, a3 = 0.f;
            #pragma unroll
            for (int kk = 0; kk < 64; kk += 4) {
                a0 += row[kk]; a1 += row[kk + 1]; a2 += row[kk + 2]; a3 += row[kk + 3];
            }
            pbuf[0][tid] = (a0 + a1) + (a2 + a3);
        } else if (tid >= 64 && tid < 114) {
            const float* row = &vbuf[(tid - 64) * 129 + 64];
            float a0 = 0.f, a1 = 0.f, a2 = 0.f, a3 = 0.f;
            #pragma unroll
            for (int kk = 0; kk < 64; kk += 4) {
                a0 += row[kk]; a1 += row[kk + 1]; a2 += row[kk + 2]; a3 += row[kk + 3];
            }
            pbuf[1][tid - 64] = (a0 + a1) + (a2 + a3);
        }
        __syncthreads();

        // 5. layer-2, 50 serial steps (redundant on all lanes)
        float my_s2 = 0.f;
        #pragma unroll
        for (int tl = 0; tl < 50; ++tl) {
            float ot = pbuf[0][tl] + pbuf[1][tl];
            float y2 = fmaf(D, Aq, CD * Ap);
            Aq = y2;
            Ap = fmaf(D, Ap, ot);
            float q2 = fmaf(D, Rq, CRD * Rp);
            float u2 = y2 + q2;
            float s2 = (u2 >= 1.0f) ? 1.0f : 0.0f;
            Rq = q2;
            Rp = fmaf(D, Rp, s2);
            if (tl == tid) my_s2 = s2;
        }
        if (tid < 50) out[(size_t)b * TT + chunk * 50 + tid] = my_s2;
        // hbuf rewrite next chunk is fenced by the step-1 barrier (two barriers
        // separate any step-3 read from the next chunk's step-1 write).
    }
}

// ---------------------------------------------------------------------------
// Fallback spmm (ws too small): round-3 kernel, h layout [t][b][ch]
// ---------------------------------------------------------------------------
__global__ __launch_bounds__(256) void spmm3_kernel(const float* __restrict__ x,
                                                    const float* __restrict__ w1t,
                                                    float* __restrict__ h) {
    __shared__ ushort lists[4][144];
    const int lane = threadIdx.x & 63;
    const int w = threadIdx.x >> 6;
    const int r = blockIdx.x * 4 + w;
    const float* xrow = x + (size_t)r * ENC;
    const unsigned long long lt = (1ull << lane) - 1ull;

    float xv[11];
    #pragma unroll
    for (int kk = 0; kk < 11; ++kk) {
        int c = kk * 64 + lane;
        xv[kk] = (c < ENC) ? xrow[c] : 0.0f;
    }
    int base = 0;
    #pragma unroll
    for (int kk = 0; kk < 11; ++kk) {
        bool act = (xv[kk] != 0.0f);
        unsigned long long m = __ballot(act);
        if (act) {
            int pos = base + (int)__popcll(m & lt);
            if (pos < 128) lists[w][pos] = (ushort)(kk * 64 + lane);
        }
        base += (int)__popcll(m);
    }
    int n = (base < 128) ? base : 128;
    int npad = (n + 15) & ~15;
    if (lane < npad - n) lists[w][n + lane] = (ushort)ENC;
    __syncthreads();

    float accx = 0.f, accy = 0.f;
    for (int j = 0; j < npad; j += 16) {
        int c0  = lists[w][j + 0],  c1  = lists[w][j + 1];
        int c2  = lists[w][j + 2],  c3  = lists[w][j + 3];
        int c4  = lists[w][j + 4],  c5  = lists[w][j + 5];
        int c6  = lists[w][j + 6],  c7  = lists[w][j + 7];
        int c8  = lists[w][j + 8],  c9  = lists[w][j + 9];
        int c10 = lists[w][j + 10], c11 = lists[w][j + 11];
        int c12 = lists[w][j + 12], c13 = lists[w][j + 13];
        int c14 = lists[w][j + 14], c15 = lists[w][j + 15];
        float2 t0  = ((const float2*)(w1t + (size_t)c0  * HID))[lane];
        float2 t1  = ((const float2*)(w1t + (size_t)c1  * HID))[lane];
        float2 t2  = ((const float2*)(w1t + (size_t)c2  * HID))[lane];
        float2 t3  = ((const float2*)(w1t + (size_t)c3  * HID))[lane];
        float2 t4  = ((const float2*)(w1t + (size_t)c4  * HID))[lane];
        float2 t5  = ((const float2*)(w1t + (size_t)c5  * HID))[lane];
        float2 t6  = ((const float2*)(w1t + (size_t)c6  * HID))[lane];
        float2 t7  = ((const float2*)(w1t + (size_t)c7  * HID))[lane];
        float2 t8  = ((const float2*)(w1t + (size_t)c8  * HID))[lane];
        float2 t9  = ((const float2*)(w1t + (size_t)c9  * HID))[lane];
        float2 t10 = ((const float2*)(w1t + (size_t)c10 * HID))[lane];
        float2 t11 = ((const float2*)(w1t + (size_t)c11 * HID))[lane];
        float2 t12 = ((const float2*)(w1t + (size_t)c12 * HID))[lane];
        float2 t13 = ((const float2*)(w1t + (size_t)c13 * HID))[lane];
        float2 t14 = ((const float2*)(w1t + (size_t)c14 * HID))[lane];
        float2 t15 = ((const float2*)(w1t + (size_t)c15 * HID))[lane];
        accx += t0.x;  accy += t0.y;  accx += t1.x;  accy += t1.y;
        accx += t2.x;  accy += t2.y;  accx += t3.x;  accy += t3.y;
        accx += t4.x;  accy += t4.y;  accx += t5.x;  accy += t5.y;
        accx += t6.x;  accy += t6.y;  accx += t7.x;  accy += t7.y;
        accx += t8.x;  accy += t8.y;  accx += t9.x;  accy += t9.y;
        accx += t10.x; accy += t10.y; accx += t11.x; accy += t11.y;
        accx += t12.x; accy += t12.y; accx += t13.x; accy += t13.y;
        accx += t14.x; accy += t14.y; accx += t15.x; accy += t15.y;
    }
    int b = r / TT;
    int t = r - b * TT;
    float2* dst = (float2*)(h + (size_t)t * (BB * HID) + (size_t)b * HID);
    dst[lane] = make_float2(accx, accy);
}

// ---------------------------------------------------------------------------
extern "C" void kernel_launch(void* const* d_in, const int* in_sizes, int n_in,
                              void* d_out, int out_size, void* d_ws, size_t ws_size,
                              hipStream_t stream) {
    const float* x  = (const float*)d_in[0];   // (B, T, ENC) binary fp32
    const float* w1 = (const float*)d_in[1];   // (HID, ENC)
    const float* w2 = (const float*)d_in[2];   // (1, HID)
    float* out = (float*)d_out;                // (B, T, 1)

    const size_t H_ELEMS   = (size_t)TT * BB * HID;
    const size_t W1T_ELEMS = (size_t)ENC_PAD * HID;
    float* h   = (float*)d_ws;
    float* w1t = h + H_ELEMS;
    char* base2 = (char*)(w1t + W1T_ELEMS);
    uint* lists = (uint*)base2;                               // 40.96 MB
    int* ncnt = (int*)(base2 + (size_t)BB * TT * LMAX * 4);   // 0.51 MB
    const size_t NEED = (size_t)(base2 - (char*)d_ws) +
                        (size_t)BB * TT * LMAX * 4 + (size_t)BB * TT * 4;

    hipLaunchKernelGGL(transpose_w1_kernel, dim3(ENC_PAD), dim3(HID), 0, stream, w1, w1t);
    if (ws_size >= NEED) {
        hipLaunchKernelGGL(compress2_kernel, dim3((BB * TT) / 4), dim3(256), 0, stream,
                           x, lists, ncnt);
        hipLaunchKernelGGL(gather3_kernel, dim3(BB * TT / GROWS, HID / QCH), dim3(256),
                           0, stream, lists, ncnt, w1t, h);
    } else {
        hipLaunchKernelGGL(spmm3_kernel, dim3((BB * TT) / 4), dim3(256), 0, stream,
                           x, w1t, h);
    }
    hipLaunchKernelGGL(recur2_kernel, dim3(BB), dim3(128), 0, stream, h, w2, out);
}